// Round 5
// baseline (58.772 us; speedup 1.0000x reference)
//
#include <hip/hip_runtime.h>

// SITH: out[t,o,f] = subset[o] * sum_n invL_sub[o,n] * ts[t,n,f]
//   ts[t,n,f] = d[n]*ts[t-1,n,f] + decay[n]*inp[t,f]
// invL_sub row o is exactly banded: nonzero only n in [4o, 4o+8].
//
// R5 vs R4:
//  - pass1 split into two-level scan: pass1a (per-chunk locals, 16x more
//    parallel, NPT=8) + pass1b (in-place cross-chunk scan with d^32).
//  - pass2 stores are plain (dropped nontemporal) as an A/B on store BW.

#define SEQL 512
#define NF   512
#define NN   408
#define NO   100
#define NC   16     // time chunks
#define TC   32     // steps per chunk
#define NB   15     // boundary states needed (chunks 0..14)
#define TAPS 11
#define OPG  5      // outputs per o-group
#define NG   20     // o-groups (NG*OPG == NO)
#define ROWS 27     // state rows per o-group window [20g-1, 20g+25]
#define NPT  8      // n-rows per pass1a thread

// ---------------- Pass 1a: per-chunk local scan sums ----------------
// L[b][n][f] = sum_i d[n]^(TC-1-i) * g[n] * x[b*TC+i, f],  b = 0..14
__global__ __launch_bounds__(256) void sith_pass1a(
    const float* __restrict__ inp, const float* __restrict__ d,
    const float* __restrict__ decay, float* __restrict__ L)
{
    int bid = blockIdx.x;              // 15 * 51 * 2 = 1530
    int b   = bid / 102;
    int rem = bid % 102;
    int nq  = rem >> 1;
    int f   = (rem & 1) * 256 + threadIdx.x;
    int n0  = nq * NPT;

    float dreg[NPT], greg[NPT], st[NPT];
    #pragma unroll
    for (int q = 0; q < NPT; ++q) {
        dreg[q] = d[n0 + q];
        greg[q] = decay[n0 + q];
        st[q] = 0.f;
    }

    const float* ip = inp + b * TC * NF + f;
    #pragma unroll
    for (int tt = 0; tt < TC; tt += 8) {
        float x[8];
        #pragma unroll
        for (int u = 0; u < 8; ++u)
            x[u] = ip[(tt + u) * NF];
        #pragma unroll
        for (int u = 0; u < 8; ++u) {
            #pragma unroll
            for (int q = 0; q < NPT; ++q)
                st[q] = fmaf(dreg[q], st[q], greg[q] * x[u]);
        }
    }
    #pragma unroll
    for (int q = 0; q < NPT; ++q)
        L[b * (NN * NF) + (n0 + q) * NF + f] = st[q];
}

// ---------------- Pass 1b: cross-chunk scan (in place) ----------------
// S_b = L_b + d^32 * S_{b-1}; S_0 = L_0. Overwrites L with S.
__global__ __launch_bounds__(256) void sith_pass1b(
    const float* __restrict__ d, float* __restrict__ S)
{
    int gid = blockIdx.x * 256 + threadIdx.x;   // 408*512 threads
    int n = gid >> 9;
    float dn = d[n];
    float d2 = dn * dn, d4 = d2 * d2, d8 = d4 * d4, d16 = d8 * d8;
    float d32 = d16 * d16;

    float v[NB];
    #pragma unroll
    for (int b = 0; b < NB; ++b)
        v[b] = S[b * (NN * NF) + gid];          // independent loads
    float acc = v[0];
    #pragma unroll
    for (int b = 1; b < NB; ++b) {
        acc = fmaf(d32, acc, v[b]);
        S[b * (NN * NF) + gid] = acc;
    }
}

// ---------------- Pass 2: per-chunk scan + banded projection ----------------
// block = (chunk c, o-chunk oc, f-slice fs). 256 threads = 4 waves.
// lane = f (64 consecutive), wave w -> o-group g = oc*4 + w (5 outputs).
__global__ __launch_bounds__(256) void sith_pass2(
    const float* __restrict__ inp, const float* __restrict__ invL,
    const float* __restrict__ d, const float* __restrict__ decay,
    const float* __restrict__ subset, const float* __restrict__ S,
    float* __restrict__ out)
{
    int bid = blockIdx.x;                 // 16c * 5oc * 8fs = 640
    int fs = bid & 7;
    int r  = bid >> 3;
    int oc = r % 5;
    int c  = r / 5;
    int tid = threadIdx.x;
    int lane = tid & 63;
    int w = tid >> 6;
    int g = oc * 4 + w;                   // 0..19
    int f = fs * 64 + lane;
    int nbase = NG * g - 1;               // row j -> n = nbase + j, j in [0,27)

    float dreg[ROWS], greg[ROWS], st[ROWS];
    #pragma unroll
    for (int j = 0; j < ROWS; ++j) {
        int n = nbase + j;
        bool v = (n >= 0);                // n <= 405 < 408 always
        int ncl = v ? n : 0;
        dreg[j] = v ? d[ncl] : 0.f;
        greg[j] = v ? decay[ncl] : 0.f;
        if (c == 0) st[j] = 0.f;
        else        st[j] = v ? S[(c - 1) * (NN * NF) + ncl * NF + f] : 0.f;
    }

    float L[OPG][TAPS];
    #pragma unroll
    for (int k = 0; k < OPG; ++k) {
        int o = OPG * g + k;              // < 100 always
        float sub = subset[o];
        #pragma unroll
        for (int dd = 0; dd < TAPS; ++dd) {
            int n = nbase + 4 * k + dd;   // = 4o - 1 + dd
            bool v = (n >= 0);
            L[k][dd] = v ? invL[o * NN + n] * sub : 0.f;
        }
    }

    const float* ip = inp + f;
    int t0 = c * TC;
    int obase = (t0 * NO + OPG * g) * NF + f;

#define SITH_STEP(xv)                                                      \
    {                                                                      \
        _Pragma("unroll")                                                  \
        for (int j = 0; j < ROWS; ++j)                                     \
            st[j] = fmaf(dreg[j], st[j], greg[j] * (xv));                  \
        _Pragma("unroll")                                                  \
        for (int k = 0; k < OPG; ++k) {                                    \
            float acc = 0.f;                                               \
            _Pragma("unroll")                                              \
            for (int dd = 0; dd < TAPS; ++dd)                              \
                acc = fmaf(L[k][dd], st[4 * k + dd], acc);                 \
            out[obase + k * NF] = acc;                                     \
        }                                                                  \
        obase += NO * NF;                                                  \
    }

    for (int tq = 0; tq < TC; tq += 4) {
        float x0 = ip[(t0 + tq + 0) * NF];
        float x1 = ip[(t0 + tq + 1) * NF];
        float x2 = ip[(t0 + tq + 2) * NF];
        float x3 = ip[(t0 + tq + 3) * NF];
        SITH_STEP(x0);
        SITH_STEP(x1);
        SITH_STEP(x2);
        SITH_STEP(x3);
    }
#undef SITH_STEP
}

extern "C" void kernel_launch(void* const* d_in, const int* in_sizes, int n_in,
                              void* d_out, int out_size, void* d_ws, size_t ws_size,
                              hipStream_t stream)
{
    const float* inp    = (const float*)d_in[0];
    const float* invL   = (const float*)d_in[1];
    const float* d      = (const float*)d_in[2];
    const float* decay  = (const float*)d_in[3];
    const float* subset = (const float*)d_in[4];
    float* out = (float*)d_out;
    float* S   = (float*)d_ws;   // 15 * 408 * 512 * 4 B = 12.5 MB (locals -> boundaries)

    sith_pass1a<<<NB * (NN / NPT) * (NF / 256), 256, 0, stream>>>(inp, d, decay, S);
    sith_pass1b<<<(NN * NF) / 256, 256, 0, stream>>>(d, S);
    sith_pass2<<<NC * 5 * 8, 256, 0, stream>>>(inp, invL, d, decay, subset, S, out);
}

// Round 9
// 45.265 us; speedup vs baseline: 1.2984x; 1.2984x over previous
//
#include <hip/hip_runtime.h>

// SITH: out[t,o,f] = subset[o] * sum_n invL_sub[o,n] * ts[t,n,f]
//   ts[t,n,f] = d[n]*ts[t-1,n,f] + decay[n]*inp[t,f]
// invL_sub row o is EXACTLY banded: nonzero only n in [4o, 4o+8] (9 taps).
//
// R7 vs R4:
//  - unscaled state p = d*p + x (decay folded into taps): pass1 VALU /2,
//    pass2 recurrence 54 -> 25 ops/step.
//  - exact 9-tap band, ROWS=25, nbase=20g >= 0: all guards gone,
//    projection 55 -> 45 FMA/step.

#define NF   512
#define NN   408
#define NO   100
#define NC   16     // time chunks
#define TC   32     // steps per chunk
#define NB   15     // boundary states stored (chunks 0..14)
#define TAPS 9
#define OPG  5      // outputs per o-group
#define NG   20     // o-groups (NG*OPG == NO)
#define ROWS 25     // state rows per o-group window [20g, 20g+24]
#define NPT  4      // n-rows per pass1 thread

// ---------------- Pass 1: chunk-boundary unscaled states ----------------
// thread = (n-quad, f); p = d*p + x, one x load feeds 4 single-FMA chains.
__global__ __launch_bounds__(256) void sith_pass1(
    const float* __restrict__ inp, const float* __restrict__ d,
    float* __restrict__ P)
{
    int gid = blockIdx.x * 256 + threadIdx.x;      // 102*512 threads
    int nq = gid >> 9;                             // n-quad 0..101
    int f  = gid & (NF - 1);
    int n0 = nq * NPT;

    float dreg[NPT], st[NPT];
    #pragma unroll
    for (int q = 0; q < NPT; ++q) {
        dreg[q] = d[n0 + q];
        st[q] = 0.f;
    }

    const float* ip = inp + f;
    for (int b = 0; b < NB; ++b) {                 // last chunk never stored
        #pragma unroll
        for (int tt = 0; tt < TC; tt += 8) {
            float x[8];
            #pragma unroll
            for (int u = 0; u < 8; ++u)
                x[u] = ip[(b * TC + tt + u) * NF];
            #pragma unroll
            for (int u = 0; u < 8; ++u) {
                #pragma unroll
                for (int q = 0; q < NPT; ++q)
                    st[q] = fmaf(dreg[q], st[q], x[u]);
            }
        }
        #pragma unroll
        for (int q = 0; q < NPT; ++q)
            P[b * (NN * NF) + (n0 + q) * NF + f] = st[q];
    }
}

// ---------------- Pass 2: per-chunk scan + banded projection ----------------
// block = (chunk c, o-chunk oc, f-slice fs). 256 threads = 4 waves.
// lane = f (64 consecutive), wave w -> o-group g = oc*4 + w (5 outputs).
// Taps carry invL * subset * decay; state is unscaled p.
__global__ __launch_bounds__(256) void sith_pass2(
    const float* __restrict__ inp, const float* __restrict__ invL,
    const float* __restrict__ d, const float* __restrict__ decay,
    const float* __restrict__ subset, const float* __restrict__ P,
    float* __restrict__ out)
{
    int bid = blockIdx.x;                 // 16c * 5oc * 8fs = 640
    int fs = bid & 7;
    int r  = bid >> 3;
    int oc = r % 5;
    int c  = r / 5;
    int tid = threadIdx.x;
    int lane = tid & 63;
    int w = tid >> 6;
    int g = oc * 4 + w;                   // 0..19
    int f = fs * 64 + lane;
    int nbase = NG * g;                   // row j -> n = nbase + j, j in [0,25)

    float dreg[ROWS], p[ROWS];
    #pragma unroll
    for (int j = 0; j < ROWS; ++j) {
        int n = nbase + j;                // 20g .. 20g+24 <= 404 < 408: no guards
        dreg[j] = d[n];
        p[j] = (c == 0) ? 0.f : P[(c - 1) * (NN * NF) + n * NF + f];
    }

    float L[OPG][TAPS];
    #pragma unroll
    for (int k = 0; k < OPG; ++k) {
        int o = OPG * g + k;              // < 100 always
        float sub = subset[o];
        #pragma unroll
        for (int dd = 0; dd < TAPS; ++dd) {
            int n = nbase + 4 * k + dd;   // = 4o + dd, exact band
            L[k][dd] = invL[o * NN + n] * sub * decay[n];
        }
    }

    const float* ip = inp + f;
    int t0 = c * TC;
    int obase = (t0 * NO + OPG * g) * NF + f;

#define SITH_STEP(xv)                                                      \
    {                                                                      \
        _Pragma("unroll")                                                  \
        for (int j = 0; j < ROWS; ++j)                                     \
            p[j] = fmaf(dreg[j], p[j], (xv));                              \
        _Pragma("unroll")                                                  \
        for (int k = 0; k < OPG; ++k) {                                    \
            float acc = 0.f;                                               \
            _Pragma("unroll")                                              \
            for (int dd = 0; dd < TAPS; ++dd)                              \
                acc = fmaf(L[k][dd], p[4 * k + dd], acc);                  \
            __builtin_nontemporal_store(acc, &out[obase + k * NF]);        \
        }                                                                  \
        obase += NO * NF;                                                  \
    }

    for (int tq = 0; tq < TC; tq += 4) {
        float x0 = ip[(t0 + tq + 0) * NF];
        float x1 = ip[(t0 + tq + 1) * NF];
        float x2 = ip[(t0 + tq + 2) * NF];
        float x3 = ip[(t0 + tq + 3) * NF];
        SITH_STEP(x0);
        SITH_STEP(x1);
        SITH_STEP(x2);
        SITH_STEP(x3);
    }
#undef SITH_STEP
}

extern "C" void kernel_launch(void* const* d_in, const int* in_sizes, int n_in,
                              void* d_out, int out_size, void* d_ws, size_t ws_size,
                              hipStream_t stream)
{
    const float* inp    = (const float*)d_in[0];
    const float* invL   = (const float*)d_in[1];
    const float* d      = (const float*)d_in[2];
    const float* decay  = (const float*)d_in[3];
    const float* subset = (const float*)d_in[4];
    float* out = (float*)d_out;
    float* P   = (float*)d_ws;   // 15 * 408 * 512 * 4 B = 12.5 MB boundary states

    sith_pass1<<<(NN / NPT) * (NF / 256), 256, 0, stream>>>(inp, d, P);
    sith_pass2<<<NC * 5 * 8, 256, 0, stream>>>(inp, invL, d, decay, subset, P, out);
}